// Round 12
// baseline (152.043 us; speedup 1.0000x reference)
//
#include <hip/hip_runtime.h>

#define CH 64
#define RPW 8              // rows per wave
#define WPB 4              // waves per block
#define BLOCK (WPB * 64)

typedef short short8 __attribute__((ext_vector_type(8)));
typedef _Float16 half8 __attribute__((ext_vector_type(8)));
typedef float f32x4 __attribute__((ext_vector_type(4)));
typedef unsigned short ushort8v __attribute__((ext_vector_type(8)));
typedef _Float16 half2v __attribute__((ext_vector_type(2)));

__device__ __forceinline__ unsigned short f2bf(float f) {
    unsigned u = __float_as_uint(f);
    u += 0x7fff + ((u >> 16) & 1);          // round-to-nearest-even
    return (unsigned short)(u >> 16);
}
__device__ __forceinline__ float bf2f(unsigned short h) {
    return __uint_as_float(((unsigned)h) << 16);
}
__device__ __forceinline__ unsigned pkh2(float a, float b) {
    union { half2v h; unsigned u; } cv;
    cv.h = half2v{(_Float16)a, (_Float16)b};
    return cv.u;
}

union U8h { unsigned u[4]; half8 h; };

// Kernel A: row_ptr[r] = first edge index e with edge_row[e] >= r  (r in [0, N])
__global__ __launch_bounds__(256) void build_row_ptr(
    const int* __restrict__ erow, int* __restrict__ rp, int N, int E)
{
    int r = blockIdx.x * 256 + threadIdx.x;
    if (r > N) return;
    int lo = 0, len = E;
    while (len > 0) {
        int half = len >> 1;
        int probe = lo + half;
        int v = erow[probe];
        if (v < r) { lo = probe + 1; len -= half + 1; }
        else { len = half; }
    }
    rp[r] = lo;
}

// Kernel A2: W as bf16 hi/lo fragments in mfma_16x16x32 B-layout (validated r8).
// ws layout: wf[((h*4+ks)*4+nt)*512 + lane*8 + j]
__global__ __launch_bounds__(256) void prep_wfrag(
    const float* __restrict__ W, unsigned short* __restrict__ wf)
{
    int tid = blockIdx.x * 256 + threadIdx.x;
    if (tid >= 2048) return;
    int lane = tid & 63;
    int nt = (tid >> 6) & 3;
    int ks = (tid >> 8) & 3;
    int h  = (tid >> 10) & 1;
    int n  = nt * 16 + (lane & 15);
    int g  = lane >> 4;
    ushort8v o;
    #pragma unroll
    for (int j = 0; j < 8; ++j) {
        int kk = ks * 32 + g * 8 + j;
        float w = (kk < 64) ? W[kk * 64 + n] : W[4096 + (kk - 64) * 64 + n];
        unsigned short hi = f2bf(w);
        o[j] = h ? f2bf(w - bf2f(hi)) : hi;
    }
    *(ushort8v*)(wf + (size_t)tid * 8) = o;
}

// Kernel A3: pack X as interleaved f16 pairs: Xp[i] = h(Xi)<<16 | h(Xr)
__global__ __launch_bounds__(256) void pack_x(
    const float* __restrict__ Xr, const float* __restrict__ Xi,
    unsigned* __restrict__ Xp, int total4)
{
    int i = blockIdx.x * 256 + threadIdx.x;
    if (i >= total4) return;
    float4 r  = ((const float4*)Xr)[i];
    float4 im = ((const float4*)Xi)[i];
    uint4 o;
    o.x = pkh2(r.x, im.x);
    o.y = pkh2(r.y, im.y);
    o.z = pkh2(r.z, im.z);
    o.w = pkh2(r.w, im.w);
    ((uint4*)Xp)[i] = o;
}

// Fallback (only if ws too small -- never expected): simple correct kernel.
__global__ __launch_bounds__(64) void sdconv_naive(
    const float* __restrict__ Xr, const float* __restrict__ Xi,
    const float* __restrict__ Lr, const float* __restrict__ Li,
    const float* __restrict__ W, const float* __restrict__ bias,
    const int* __restrict__ ecol, const int* __restrict__ rp,
    float* __restrict__ outR, float* __restrict__ outI, int N, int E)
{
    int row = blockIdx.x;
    int lane = threadIdx.x;
    if (row >= N) return;
    __shared__ float s[4][64];
    float a0 = 0.f, b0 = 0.f, a1 = 0.f, b1 = 0.f;
    for (int e = rp[row]; e < rp[row + 1]; ++e) {
        int c = ecol[e];
        float xr = Xr[(size_t)c * 64 + lane], xi = Xi[(size_t)c * 64 + lane];
        float l0r = Lr[e], l0i = Li[e], l1r = Lr[E + e], l1i = Li[E + e];
        a0 += l0r * xr - l0i * xi;  b0 += l0i * xr + l0r * xi;
        a1 += l1r * xr - l1i * xi;  b1 += l1i * xr + l1r * xi;
    }
    s[0][lane] = a0; s[1][lane] = a1; s[2][lane] = b0; s[3][lane] = b1;
    __syncthreads();
    float oR = bias[lane], oI = bias[lane];
    for (int c = 0; c < 64; ++c) {
        float w0 = W[c * 64 + lane], w1 = W[4096 + c * 64 + lane];
        oR += s[0][c] * w0 + s[1][c] * w1;
        oI += s[2][c] * w0 + s[3][c] * w1;
    }
    outR[(size_t)row * 64 + lane] = oR;
    outI[(size_t)row * 64 + lane] = oI;
}

// Kernel B: MFMA spmm (r11 structure, two fixes):
//  FIX 1: variant->array staging order {a0,b0,a1,b1} -> arrays {0,2,1,3}
//          (epilogue convention: 0=a0, 1=a1, 2=b0, 3=b1). r11 wrote v->v,
//          computing a0*w0+b0*w1 -- the full-scale failure.
//  FIX 2: ds_bpermute hoisted out of the select (result masked, op never
//          under divergent exec -- source-lane reads stay valid).
__global__ __launch_bounds__(BLOCK, 3) void sdconv_fused(
    const unsigned* __restrict__ Xp,
    const float* __restrict__ Lr, const float* __restrict__ Li,
    const float* __restrict__ bias,
    const int* __restrict__ ecol, const int* __restrict__ rp,
    const unsigned short* __restrict__ wf,
    float* __restrict__ outR, float* __restrict__ outI,
    int N, int E)
{
    __shared__ float sA[WPB][4 * RPW * 68];   // per-wave slice: [4 arr][8 rows][68]

    const int t    = threadIdx.x;
    const int wave = t >> 6;
    const int lane = t & 63;
    const int me   = lane & 15;
    const int g    = lane >> 4;
    const int r0w  = (blockIdx.x * WPB + wave) * RPW;

    int rpidx = r0w + (lane < 9 ? lane : 8);
    if (rpidx > N) rpidx = N;
    const int vrp = rp[rpidx];

    const float* __restrict__ Lr1 = Lr + E;
    const float* __restrict__ Li1 = Li + E;

    f32x4 acc[4][4];                 // [variant a0,b0,a1,b1][ch-tile]
    #pragma unroll
    for (int v = 0; v < 4; ++v)
        #pragma unroll
        for (int c = 0; c < 4; ++c)
            acc[v][c] = (f32x4){0.f, 0.f, 0.f, 0.f};

    for (int tr = 0; tr < RPW; ++tr) {
        const int s  = __builtin_amdgcn_readlane(vrp, tr);
        const int e2 = __builtin_amdgcn_readlane(vrp, tr + 1);
        const unsigned amask = (me == tr) ? 0xffffffffu : 0u;
        for (int wb = s; wb < e2; wb += 64) {
            // coalesced 64-edge window: cols + 4 packed L-pair variants
            int  eid  = wb + lane;
            bool ok   = eid < e2;
            int  eidc = ok ? eid : s;
            int   vcol = ecol[eidc];
            float l0r = ok ? Lr[eidc]  : 0.f;
            float l0i = ok ? Li[eidc]  : 0.f;
            float l1r = ok ? Lr1[eidc] : 0.f;
            float l1i = ok ? Li1[eidc] : 0.f;
            int vpk[4];
            vpk[0] = (int)pkh2(l0r, -l0i);   // -> a0
            vpk[1] = (int)pkh2(l0i,  l0r);   // -> b0
            vpk[2] = (int)pkh2(l1r, -l1i);   // -> a1
            vpk[3] = (int)pkh2(l1i,  l1r);   // -> b1

            int wlen = e2 - wb; if (wlen > 64) wlen = 64;
            int ntile = (wlen + 15) >> 4;
            for (int tt = 0; tt < ntile; ++tt) {
                const int eb  = tt * 16 + g * 4;      // this lane's 4 edge-slots
                const int ad0 = (eb + 0) * 4, ad1 = (eb + 1) * 4;
                const int ad2 = (eb + 2) * 4, ad3 = (eb + 3) * 4;
                // cols of the 4 edges (lane-varying pull = bpermute)
                int c0 = __builtin_amdgcn_ds_bpermute(ad0, vcol);
                int c1 = __builtin_amdgcn_ds_bpermute(ad1, vcol);
                int c2 = __builtin_amdgcn_ds_bpermute(ad2, vcol);
                int c3 = __builtin_amdgcn_ds_bpermute(ad3, vcol);
                // A fragments: bpermute ALL lanes (full exec), mask result.
                U8h F[4];
                #pragma unroll
                for (int v = 0; v < 4; ++v) {
                    unsigned b0_ = (unsigned)__builtin_amdgcn_ds_bpermute(ad0, vpk[v]);
                    unsigned b1_ = (unsigned)__builtin_amdgcn_ds_bpermute(ad1, vpk[v]);
                    unsigned b2_ = (unsigned)__builtin_amdgcn_ds_bpermute(ad2, vpk[v]);
                    unsigned b3_ = (unsigned)__builtin_amdgcn_ds_bpermute(ad3, vpk[v]);
                    F[v].u[0] = b0_ & amask;
                    F[v].u[1] = b1_ & amask;
                    F[v].u[2] = b2_ & amask;
                    F[v].u[3] = b3_ & amask;
                }
                // B fragments: lane (me, g) loads X[col_{eb+d}][me + 16*cht]
                unsigned o0 = ((unsigned)c0 << 6) + (unsigned)me;
                unsigned o1 = ((unsigned)c1 << 6) + (unsigned)me;
                unsigned o2 = ((unsigned)c2 << 6) + (unsigned)me;
                unsigned o3 = ((unsigned)c3 << 6) + (unsigned)me;
                U8h Bt[4];
                #pragma unroll
                for (int c = 0; c < 4; ++c) {
                    Bt[c].u[0] = Xp[o0 + c * 16];
                    Bt[c].u[1] = Xp[o1 + c * 16];
                    Bt[c].u[2] = Xp[o2 + c * 16];
                    Bt[c].u[3] = Xp[o3 + c * 16];
                }
                #pragma unroll
                for (int c = 0; c < 4; ++c)
                    #pragma unroll
                    for (int v = 0; v < 4; ++v)
                        acc[v][c] = __builtin_amdgcn_mfma_f32_16x16x32_f16(
                            F[v].h, Bt[c].h, acc[v][c], 0, 0, 0);
            }
        }
    }

    // Stage C-tiles. FIX 1: variant v={a0,b0,a1,b1} -> array {0,2,1,3}
    // (epilogue: arr0=a0, arr1=a1, arr2=b0, arr3=b1).
    // C/D: col=me, row=g*4+q; rows 0-7 live in lanes g<2.
    float* sl = sA[wave];
    if (g < 2) {
        const int arrmap[4] = {0, 2, 1, 3};
        #pragma unroll
        for (int v = 0; v < 4; ++v)
            #pragma unroll
            for (int c = 0; c < 4; ++c)
                #pragma unroll
                for (int q = 0; q < 4; ++q)
                    sl[(arrmap[v] * RPW + g * 4 + q) * 68 + c * 16 + me] = acc[v][c][q];
    }
    __asm__ volatile("s_waitcnt lgkmcnt(0)" ::: "memory");  // wave-local RAW fence

    // Epilogue (r10-validated): per kind, C2[8x64] = A2[8x128] x Wfrag[128x64]
    #pragma unroll
    for (int kind = 0; kind < 2; ++kind) {
        const int abase = kind * 2;           // arrays {0,1}=real, {2,3}=imag
        f32x4 o[4];
        #pragma unroll
        for (int nt = 0; nt < 4; ++nt) o[nt] = (f32x4){0.f, 0.f, 0.f, 0.f};
        #pragma unroll
        for (int ks = 0; ks < 4; ++ks) {
            const int kk0 = ks * 32 + g * 8;
            short8 ah = {0, 0, 0, 0, 0, 0, 0, 0};
            if (me < 8) {                     // only validated A rows carry data
                const int arr = abase + (kk0 >= 64 ? 1 : 0);
                const float* src = &sl[(arr * RPW + me) * 68 + (kk0 & 63)];
                float4 v0 = *(const float4*)src;
                float4 v1 = *(const float4*)(src + 4);
                float av[8] = {v0.x, v0.y, v0.z, v0.w, v1.x, v1.y, v1.z, v1.w};
                #pragma unroll
                for (int j = 0; j < 8; ++j) ah[j] = (short)f2bf(av[j]);
            }
            #pragma unroll
            for (int nt = 0; nt < 4; ++nt) {
                short8 bh = *(const short8*)(wf + (size_t)((0 * 4 + ks) * 4 + nt) * 512 + lane * 8);
                short8 bl = *(const short8*)(wf + (size_t)((1 * 4 + ks) * 4 + nt) * 512 + lane * 8);
                o[nt] = __builtin_amdgcn_mfma_f32_16x16x32_bf16(ah, bh, o[nt], 0, 0, 0);
                o[nt] = __builtin_amdgcn_mfma_f32_16x16x32_bf16(ah, bl, o[nt], 0, 0, 0);
            }
        }
        if (g < 2) {
            float* __restrict__ dst = kind ? outI : outR;
            #pragma unroll
            for (int nt = 0; nt < 4; ++nt) {
                float bv = bias[nt * 16 + me];
                #pragma unroll
                for (int q = 0; q < 4; ++q) {
                    int grow = r0w + g * 4 + q;
                    if (grow < N)
                        dst[(size_t)grow * CH + nt * 16 + me] = o[nt][q] + bv;
                }
            }
        }
    }
}

extern "C" void kernel_launch(void* const* d_in, const int* in_sizes, int n_in,
                              void* d_out, int out_size, void* d_ws, size_t ws_size,
                              hipStream_t stream)
{
    const float* Xr   = (const float*)d_in[0];
    const float* Xi   = (const float*)d_in[1];
    const float* Lr   = (const float*)d_in[2];
    const float* Li   = (const float*)d_in[3];
    const float* W    = (const float*)d_in[4];
    const float* bias = (const float*)d_in[5];
    const int*   erow = (const int*)d_in[6];
    const int*   ecol = (const int*)d_in[7];

    const int N = in_sizes[0] / CH;
    const int E = in_sizes[6];

    int* rp = (int*)d_ws;
    size_t woff = (((size_t)(N + 1) * 4) + 255) & ~(size_t)255;
    unsigned short* wfrag = (unsigned short*)((char*)d_ws + woff);
    size_t xoff = (woff + 32 * 1024 + 255) & ~(size_t)255;
    unsigned* Xp = (unsigned*)((char*)d_ws + xoff);
    size_t need = xoff + (size_t)N * CH * 4;

    float* outR = (float*)d_out;
    float* outI = outR + (size_t)N * CH;

    hipLaunchKernelGGL(build_row_ptr, dim3((N + 1 + 255) / 256), dim3(256), 0, stream,
                       erow, rp, N, E);

    if (ws_size >= need) {
        hipLaunchKernelGGL(prep_wfrag, dim3(8), dim3(256), 0, stream, W, wfrag);
        int total4 = N * CH / 4;
        hipLaunchKernelGGL(pack_x, dim3((total4 + 255) / 256), dim3(256), 0, stream,
                           Xr, Xi, Xp, total4);
        int nb = (N + WPB * RPW - 1) / (WPB * RPW);
        hipLaunchKernelGGL(sdconv_fused, dim3(nb), dim3(BLOCK), 0, stream,
                           Xp, Lr, Li, bias, ecol, rp, wfrag, outR, outI, N, E);
    } else {
        hipLaunchKernelGGL(sdconv_naive, dim3(N), dim3(64), 0, stream,
                           Xr, Xi, Lr, Li, W, bias, ecol, rp, outR, outI, N, E);
    }
}

// Round 13
// 120.109 us; speedup vs baseline: 1.2659x; 1.2659x over previous
//
#include <hip/hip_runtime.h>

#define CH 64
#define RPB 8
#define BLOCK (RPB * 64)

typedef short short8 __attribute__((ext_vector_type(8)));
typedef float f32x4 __attribute__((ext_vector_type(4)));
typedef unsigned short ushort8v __attribute__((ext_vector_type(8)));
typedef _Float16 half2v __attribute__((ext_vector_type(2)));

__device__ __forceinline__ unsigned short f2bf(float f) {
    unsigned u = __float_as_uint(f);
    u += 0x7fff + ((u >> 16) & 1);          // round-to-nearest-even
    return (unsigned short)(u >> 16);
}
__device__ __forceinline__ float bf2f(unsigned short h) {
    return __uint_as_float(((unsigned)h) << 16);
}
__device__ __forceinline__ unsigned pkh2(float a, float b) {
    union { half2v h; unsigned u; } cv;
    cv.h = half2v{(_Float16)a, (_Float16)b};
    return cv.u;
}
__device__ __forceinline__ half2v u2h2(unsigned u) {
    union { unsigned u; half2v h; } cv;
    cv.u = u;
    return cv.h;
}

// Kernel A: row_ptr[r] = first edge index e with edge_row[e] >= r  (r in [0, N])
__global__ __launch_bounds__(256) void build_row_ptr(
    const int* __restrict__ erow, int* __restrict__ rp, int N, int E)
{
    int r = blockIdx.x * 256 + threadIdx.x;
    if (r > N) return;
    int lo = 0, len = E;
    while (len > 0) {
        int half = len >> 1;
        int probe = lo + half;
        int v = erow[probe];
        if (v < r) { lo = probe + 1; len -= half + 1; }
        else { len = half; }
    }
    rp[r] = lo;
}

// Kernel A2: precompute W as bf16 hi/lo fragments in mfma_16x16x32 B-layout.
// (validated r8) ws layout: wf[((h*4+ks)*4+nt)*512 + lane*8 + j]
__global__ __launch_bounds__(256) void prep_wfrag(
    const float* __restrict__ W, unsigned short* __restrict__ wf)
{
    int tid = blockIdx.x * 256 + threadIdx.x;
    if (tid >= 2048) return;
    int lane = tid & 63;
    int nt = (tid >> 6) & 3;
    int ks = (tid >> 8) & 3;
    int h  = (tid >> 10) & 1;
    int n  = nt * 16 + (lane & 15);
    int g  = lane >> 4;
    ushort8v o;
    #pragma unroll
    for (int j = 0; j < 8; ++j) {
        int kk = ks * 32 + g * 8 + j;
        float w = (kk < 64) ? W[kk * 64 + n] : W[4096 + (kk - 64) * 64 + n];
        unsigned short hi = f2bf(w);
        o[j] = h ? f2bf(w - bf2f(hi)) : hi;
    }
    *(ushort8v*)(wf + (size_t)tid * 8) = o;
}

// Kernel A3: pack X as interleaved f16 pairs: Xp[i] = h(Xi)<<16 | h(Xr)
__global__ __launch_bounds__(256) void pack_x(
    const float* __restrict__ Xr, const float* __restrict__ Xi,
    unsigned* __restrict__ Xp, int total4)
{
    int i = blockIdx.x * 256 + threadIdx.x;
    if (i >= total4) return;
    float4 r  = ((const float4*)Xr)[i];
    float4 im = ((const float4*)Xi)[i];
    uint4 o;
    o.x = pkh2(r.x, im.x);
    o.y = pkh2(r.y, im.y);
    o.z = pkh2(r.z, im.z);
    o.w = pkh2(r.w, im.w);
    ((uint4*)Xp)[i] = o;
}

// ---- spmm machinery (r10 trunk); PK: f16 gathers + LDS-broadcast L + dot2 ----
#define ISSUE(BUF, SB)                                                      \
    do {                                                                    \
        _Pragma("unroll")                                                   \
        for (int j_ = 0; j_ < 8; ++j_) {                                    \
            int c_ = __builtin_amdgcn_readlane(vcol, (SB) * 8 + j_);        \
            if constexpr (PK) {                                             \
                xp##BUF[j_] = Xp[(((unsigned)c_ << 6) | (unsigned)lane)];   \
            } else {                                                        \
                xr##BUF[j_] = Xr[(size_t)c_ * CH + lane];                   \
                xi##BUF[j_] = Xi[(size_t)c_ * CH + lane];                   \
            }                                                               \
        }                                                                   \
        __builtin_amdgcn_sched_barrier(0);                                  \
    } while (0)

#define PROC(BUF, SB)                                                       \
    do {                                                                    \
        _Pragma("unroll")                                                   \
        for (int j_ = 0; j_ < 8; ++j_) {                                    \
            int k_ = (SB) * 8 + j_;                                         \
            if constexpr (PK) {                                             \
                uint4 lv_ = *(const uint4*)(Lrow + k_ * 4);  /* uniform addr -> b128 broadcast */ \
                half2v xv_ = u2h2(xp##BUF[j_]);                             \
                a0 = __builtin_amdgcn_fdot2(xv_, u2h2(lv_.x), a0, false);   \
                b0 = __builtin_amdgcn_fdot2(xv_, u2h2(lv_.y), b0, false);   \
                a1 = __builtin_amdgcn_fdot2(xv_, u2h2(lv_.z), a1, false);   \
                b1 = __builtin_amdgcn_fdot2(xv_, u2h2(lv_.w), b1, false);   \
            } else {                                                        \
                float l0r_ = __uint_as_float(__builtin_amdgcn_readlane(__float_as_uint(vl0r), k_)); \
                float l0i_ = __uint_as_float(__builtin_amdgcn_readlane(__float_as_uint(vl0i), k_)); \
                float l1r_ = __uint_as_float(__builtin_amdgcn_readlane(__float_as_uint(vl1r), k_)); \
                float l1i_ = __uint_as_float(__builtin_amdgcn_readlane(__float_as_uint(vl1i), k_)); \
                a0 += l0r_ * xr##BUF[j_] - l0i_ * xi##BUF[j_];              \
                b0 += l0i_ * xr##BUF[j_] + l0r_ * xi##BUF[j_];              \
                a1 += l1r_ * xr##BUF[j_] - l1i_ * xi##BUF[j_];              \
                b1 += l1i_ * xr##BUF[j_] + l1r_ * xi##BUF[j_];              \
            }                                                               \
        }                                                                   \
    } while (0)

template<int NSB, bool PK>
__device__ __forceinline__ void proc_row(
    int vcol, const unsigned* __restrict__ Lrow,
    float vl0r, float vl0i, float vl1r, float vl1i,
    const unsigned* __restrict__ Xp,
    const float* __restrict__ Xr, const float* __restrict__ Xi, int lane,
    float& a0, float& b0, float& a1, float& b1)
{
    unsigned xpA[8], xpB[8];
    float xrA[8], xiA[8], xrB[8], xiB[8];
    ISSUE(A, 0);
    if constexpr (NSB > 1) ISSUE(B, 1);
    PROC(A, 0);
    if constexpr (NSB > 2) ISSUE(A, 2);
    if constexpr (NSB > 1) PROC(B, 1);
    if constexpr (NSB > 3) ISSUE(B, 3);
    if constexpr (NSB > 2) PROC(A, 2);
    if constexpr (NSB > 4) ISSUE(A, 4);
    if constexpr (NSB > 3) PROC(B, 3);
    if constexpr (NSB > 5) ISSUE(B, 5);
    if constexpr (NSB > 4) PROC(A, 4);
    if constexpr (NSB > 6) ISSUE(A, 6);
    if constexpr (NSB > 5) PROC(B, 5);
    if constexpr (NSB > 7) ISSUE(B, 7);
    if constexpr (NSB > 6) PROC(A, 6);
    if constexpr (NSB > 7) PROC(B, 7);
}

// Kernel B: r10 structure; PK path broadcasts per-edge L via uniform-address
// ds_read_b128 (LDS pipe) instead of 4 readlanes (VALU pipe).
template<bool PK>
__global__ __launch_bounds__(BLOCK, 6) void sdconv_fused(
    const unsigned* __restrict__ Xp,
    const float* __restrict__ Xr, const float* __restrict__ Xi,
    const float* __restrict__ Lr, const float* __restrict__ Li,
    const float* __restrict__ bias,
    const int* __restrict__ ecol, const int* __restrict__ rp,
    const unsigned short* __restrict__ wf,
    float* __restrict__ outR, float* __restrict__ outI,
    int N, int E)
{
    // [arr(4)][blockrow(8)][68]: 0,1 = a0,a1 (real); 2,3 = b0,b1 (imag)
    __shared__ __align__(16) float sA[4 * RPB * 68];       // 8.7 KB
    __shared__ __align__(16) unsigned Lw[RPB][64][4];      // 8 KB packed L variants

    const int t    = threadIdx.x;
    const int wave = t >> 6;
    const int lane = t & 63;
    const int r0   = blockIdx.x * RPB;
    const int row  = r0 + wave;

    int start = 0, end = 0;
    if (row < N) { start = rp[row]; end = rp[row + 1]; }
    start = __builtin_amdgcn_readfirstlane(start);
    end   = __builtin_amdgcn_readfirstlane(end);

    const float* __restrict__ Lr1 = Lr + E;
    const float* __restrict__ Li1 = Li + E;
    const unsigned* __restrict__ Lrow = &Lw[wave][0][0];

    float a0 = 0.f, b0 = 0.f, a1 = 0.f, b1 = 0.f;

    for (int base = start; base < end; base += 64) {
        // one coalesced metadata round for up to 64 edges (lane j = edge j)
        int  eid  = base + lane;
        bool ok   = eid < end;
        int  eidc = ok ? eid : start;
        int   vcol = ecol[eidc];
        float vl0r = ok ? Lr[eidc]  : 0.f;
        float vl0i = ok ? Li[eidc]  : 0.f;
        float vl1r = ok ? Lr1[eidc] : 0.f;
        float vl1i = ok ? Li1[eidc] : 0.f;

        if constexpr (PK) {
            // stage packed L-pair variants for LDS broadcast in PROC
            *(uint4*)&Lw[wave][lane][0] = make_uint4(
                pkh2(vl0r, -vl0i),   // -> a0
                pkh2(vl0i,  vl0r),   // -> b0
                pkh2(vl1r, -vl1i),   // -> a1
                pkh2(vl1i,  vl1r));  // -> b1
            __asm__ volatile("s_waitcnt lgkmcnt(0)" ::: "memory");  // wave-local RAW fence
        }

        int m = end - base; if (m > 64) m = 64;   // wave-uniform
        int nsb = (m + 7) >> 3;                   // 1..8 sub-batches of 8
        switch (nsb) {
            case 1: proc_row<1, PK>(vcol, Lrow, vl0r, vl0i, vl1r, vl1i, Xp, Xr, Xi, lane, a0, b0, a1, b1); break;
            case 2: proc_row<2, PK>(vcol, Lrow, vl0r, vl0i, vl1r, vl1i, Xp, Xr, Xi, lane, a0, b0, a1, b1); break;
            case 3: proc_row<3, PK>(vcol, Lrow, vl0r, vl0i, vl1r, vl1i, Xp, Xr, Xi, lane, a0, b0, a1, b1); break;
            case 4: proc_row<4, PK>(vcol, Lrow, vl0r, vl0i, vl1r, vl1i, Xp, Xr, Xi, lane, a0, b0, a1, b1); break;
            case 5: proc_row<5, PK>(vcol, Lrow, vl0r, vl0i, vl1r, vl1i, Xp, Xr, Xi, lane, a0, b0, a1, b1); break;
            case 6: proc_row<6, PK>(vcol, Lrow, vl0r, vl0i, vl1r, vl1i, Xp, Xr, Xi, lane, a0, b0, a1, b1); break;
            case 7: proc_row<7, PK>(vcol, Lrow, vl0r, vl0i, vl1r, vl1i, Xp, Xr, Xi, lane, a0, b0, a1, b1); break;
            default: proc_row<8, PK>(vcol, Lrow, vl0r, vl0i, vl1r, vl1i, Xp, Xr, Xi, lane, a0, b0, a1, b1); break;
        }
    }

    sA[(0 * RPB + wave) * 68 + lane] = a0;
    sA[(1 * RPB + wave) * 68 + lane] = a1;
    sA[(2 * RPB + wave) * 68 + lane] = b0;
    sA[(3 * RPB + wave) * 68 + lane] = b1;
    __syncthreads();

    // Dual-chain MFMA epilogue (validated r8/r9/r10): waves 0-3 real, 4-7 imag.
    // A at bf16-hi; B keeps hi+lo split: Ah*(Bh+Bl).
    const int nt    = wave & 3;
    const int abase = (wave < 4) ? 0 : 2;
    const int cidx  = lane & 15;
    const int g     = lane >> 4;
    const int ar    = lane & 15;

    f32x4 acc = {0.f, 0.f, 0.f, 0.f};
    #pragma unroll
    for (int ks = 0; ks < 4; ++ks) {
        const int kk0 = ks * 32 + g * 8;
        short8 ah = {0, 0, 0, 0, 0, 0, 0, 0};
        if (ar < 8) {   // only validated A rows carry data
            const int arr = abase + (kk0 >= 64 ? 1 : 0);
            const float* src = &sA[(arr * RPB + ar) * 68 + (kk0 & 63)];
            float4 v0 = *(const float4*)src;
            float4 v1 = *(const float4*)(src + 4);
            float av[8] = {v0.x, v0.y, v0.z, v0.w, v1.x, v1.y, v1.z, v1.w};
            #pragma unroll
            for (int j = 0; j < 8; ++j)
                ah[j] = (short)f2bf(av[j]);
        }
        short8 bh = *(const short8*)(wf + (size_t)((0 * 4 + ks) * 4 + nt) * 512 + lane * 8);
        short8 bl = *(const short8*)(wf + (size_t)((1 * 4 + ks) * 4 + nt) * 512 + lane * 8);
        acc = __builtin_amdgcn_mfma_f32_16x16x32_bf16(ah, bh, acc, 0, 0, 0);
        acc = __builtin_amdgcn_mfma_f32_16x16x32_bf16(ah, bl, acc, 0, 0, 0);
    }

    // C/D: col=lane&15, row=(lane>>4)*4+q -> rows 0-7 live in lanes g<2
    if (g < 2) {
        float bv = bias[nt * 16 + cidx];
        float* dst = (wave < 4) ? outR : outI;
        #pragma unroll
        for (int q = 0; q < 4; ++q) {
            int grow = r0 + g * 4 + q;
            if (grow < N)
                dst[(size_t)grow * CH + nt * 16 + cidx] = acc[q] + bv;
        }
    }
}

extern "C" void kernel_launch(void* const* d_in, const int* in_sizes, int n_in,
                              void* d_out, int out_size, void* d_ws, size_t ws_size,
                              hipStream_t stream)
{
    const float* Xr   = (const float*)d_in[0];
    const float* Xi   = (const float*)d_in[1];
    const float* Lr   = (const float*)d_in[2];
    const float* Li   = (const float*)d_in[3];
    const float* W    = (const float*)d_in[4];
    const float* bias = (const float*)d_in[5];
    const int*   erow = (const int*)d_in[6];
    const int*   ecol = (const int*)d_in[7];

    const int N = in_sizes[0] / CH;
    const int E = in_sizes[6];

    int* rp = (int*)d_ws;
    size_t woff = (((size_t)(N + 1) * 4) + 255) & ~(size_t)255;
    unsigned short* wfrag = (unsigned short*)((char*)d_ws + woff);
    size_t xoff = (woff + 32 * 1024 + 255) & ~(size_t)255;
    unsigned* Xp = (unsigned*)((char*)d_ws + xoff);
    size_t need = xoff + (size_t)N * CH * 4;

    float* outR = (float*)d_out;
    float* outI = outR + (size_t)N * CH;

    hipLaunchKernelGGL(build_row_ptr, dim3((N + 1 + 255) / 256), dim3(256), 0, stream,
                       erow, rp, N, E);
    hipLaunchKernelGGL(prep_wfrag, dim3(8), dim3(256), 0, stream, W, wfrag);

    int nb = (N + RPB - 1) / RPB;
    if (ws_size >= need) {
        int total4 = N * CH / 4;
        hipLaunchKernelGGL(pack_x, dim3((total4 + 255) / 256), dim3(256), 0, stream,
                           Xr, Xi, Xp, total4);
        hipLaunchKernelGGL(sdconv_fused<true>, dim3(nb), dim3(BLOCK), 0, stream,
                           Xp, Xr, Xi, Lr, Li, bias, ecol, rp, wfrag, outR, outI, N, E);
    } else {
        hipLaunchKernelGGL(sdconv_fused<false>, dim3(nb), dim3(BLOCK), 0, stream,
                           (const unsigned*)nullptr, Xr, Xi, Lr, Li, bias, ecol, rp,
                           wfrag, outR, outI, N, E);
    }
}